// Round 1
// baseline (150.058 us; speedup 1.0000x reference)
//
#include <hip/hip_runtime.h>

// Problem constants (fixed by setup_inputs).
constexpr int Bn = 512;     // batch rows
constexpr int Ln = 512;     // sequence length
constexpr int Fn = 64;      // feature dim
constexpr int Vn = 20000;   // num_nodes (vocab)
constexpr int HWORDS = (Vn + 2) / 3;  // 10-bit-packed histogram words (3 counts/u32)

// table[v][j] = sum_i relu(v*W1[i] + b1[i]) * W2[i*F + j] + b2[j]
// (b2 appears once per channel in the reference; output = f(c0)+f(c1) gives 2*b2 total.)
__global__ void build_table_kernel(const float* __restrict__ W1,
                                   const float* __restrict__ b1,
                                   const float* __restrict__ W2,
                                   const float* __restrict__ b2,
                                   float* __restrict__ table) {
    const int v = blockIdx.x;   // count value 0..512
    const int j = threadIdx.x;  // output feature
    __shared__ float h[Fn];
    h[j] = fmaxf((float)v * W1[j] + b1[j], 0.0f);
    __syncthreads();
    float acc = b2[j];
#pragma unroll
    for (int i = 0; i < Fn; ++i)
        acc = fmaf(h[i], W2[i * Fn + j], acc);  // coalesced W2 column read across j
    table[v * Fn + j] = acc;
}

__device__ __forceinline__ unsigned hist_get(const unsigned* __restrict__ h, int v) {
    const int w = v / 3;
    const int f = v - w * 3;
    return (h[w] >> (10 * f)) & 0x3FFu;
}

__global__ __launch_bounds__(256) void comco_kernel(
    const int* __restrict__ src_ids,
    const int* __restrict__ dst_ids,
    const float* __restrict__ table,
    float* __restrict__ out_src,
    float* __restrict__ out_dst) {
    // 10-bit packed per-row histograms: counts <= 512 < 1024, so field atomics
    // can never carry into a neighboring field. 2 x 26.7 KB = 53.3 KB LDS.
    __shared__ unsigned hs[HWORDS];
    __shared__ unsigned hd[HWORDS];

    const int b = blockIdx.x;
    const int tid = threadIdx.x;

    for (int i = tid; i < HWORDS; i += 256) { hs[i] = 0u; hd[i] = 0u; }
    __syncthreads();

    const int* __restrict__ srow = src_ids + b * Ln;
    const int* __restrict__ drow = dst_ids + b * Ln;

    for (int l = tid; l < Ln; l += 256) {
        const int s = srow[l];
        const int sw = s / 3;
        atomicAdd(&hs[sw], 1u << (10 * (s - sw * 3)));
        const int d = drow[l];
        const int dw = d / 3;
        atomicAdd(&hd[dw], 1u << (10 * (d - dw * 3)));
    }
    __syncthreads();

    // Output phase: 16 threads cooperate on one position's 64 floats.
    // Wave = 4 groups -> a wave store covers 1 KB contiguous (fully coalesced).
    const int g = tid >> 4;   // group id 0..15
    const int r = tid & 15;   // float4 slot within the 64-float feature vector

    for (int l = g; l < Ln; l += 16) {
        const int sid = srow[l];
        const int did = drow[l];
        // id 0 is padding: both count channels forced to 0 (reference `where`).
        unsigned c_ss = 0, c_sd = 0, c_ds = 0, c_dd = 0;
        if (sid != 0) { c_ss = hist_get(hs, sid); c_sd = hist_get(hd, sid); }
        if (did != 0) { c_ds = hist_get(hs, did); c_dd = hist_get(hd, did); }

        const float4 t0 = *((const float4*)(table + c_ss * Fn) + r);
        const float4 t1 = *((const float4*)(table + c_sd * Fn) + r);
        const float4 u0 = *((const float4*)(table + c_ds * Fn) + r);
        const float4 u1 = *((const float4*)(table + c_dd * Fn) + r);

        float4 os, od;
        os.x = t0.x + t1.x; os.y = t0.y + t1.y; os.z = t0.z + t1.z; os.w = t0.w + t1.w;
        od.x = u0.x + u1.x; od.y = u0.y + u1.y; od.z = u0.z + u1.z; od.w = u0.w + u1.w;

        const size_t pos = (size_t)(b * Ln + l) * Fn;
        *((float4*)(out_src + pos) + r) = os;
        *((float4*)(out_dst + pos) + r) = od;
    }
}

extern "C" void kernel_launch(void* const* d_in, const int* in_sizes, int n_in,
                              void* d_out, int out_size, void* d_ws, size_t ws_size,
                              hipStream_t stream) {
    const int*   src_ids = (const int*)d_in[0];
    const int*   dst_ids = (const int*)d_in[1];
    const float* W1      = (const float*)d_in[2];
    const float* b1      = (const float*)d_in[3];
    const float* W2      = (const float*)d_in[4];
    const float* b2      = (const float*)d_in[5];
    // d_in[6] = num_nodes scalar (20000) — hardcoded as Vn.

    float* table   = (float*)d_ws;               // 513*64*4 = 131 KB scratch
    float* out_src = (float*)d_out;
    float* out_dst = out_src + (size_t)Bn * Ln * Fn;

    // Table: one block per count value 0..512, one thread per output feature.
    build_table_kernel<<<Ln + 1, Fn, 0, stream>>>(W1, b1, W2, b2, table);
    // Main: one block per row.
    comco_kernel<<<Bn, 256, 0, stream>>>(src_ids, dst_ids, table, out_src, out_dst);
}

// Round 2
// 149.866 us; speedup vs baseline: 1.0013x; 1.0013x over previous
//
#include <hip/hip_runtime.h>

// Problem constants (fixed by setup_inputs).
constexpr int Bn = 512;               // batch rows
constexpr int Ln = 512;               // sequence length
constexpr int Fn = 64;                // feature dim
constexpr int Vn = 20000;             // num_nodes (vocab)
constexpr int HWORDS = (Vn + 2) / 3;  // 10-bit-packed histogram words (3 counts/u32)
constexpr int BL = Bn * Ln;           // positions per channel = 262144 = 2^18

// table[v][j] = sum_i relu(v*W1[i] + b1[i]) * W2[i*F + j] + b2[j]
__global__ void build_table_kernel(const float* __restrict__ W1,
                                   const float* __restrict__ b1,
                                   const float* __restrict__ W2,
                                   const float* __restrict__ b2,
                                   float* __restrict__ table) {
    const int v = blockIdx.x;   // count value 0..512
    const int j = threadIdx.x;  // output feature
    __shared__ float h[Fn];
    h[j] = fmaxf((float)v * W1[j] + b1[j], 0.0f);
    __syncthreads();
    float acc = b2[j];
#pragma unroll
    for (int i = 0; i < Fn; ++i)
        acc = fmaf(h[i], W2[i * Fn + j], acc);
    table[v * Fn + j] = acc;
}

__device__ __forceinline__ unsigned hist_get(const unsigned* __restrict__ h, int v) {
    const int w = v / 3;
    const int f = v - w * 3;
    return (h[w] >> (10 * f)) & 0x3FFu;
}

// Phase 1: per-row LDS histograms -> packed per-position counts (2 MB total).
// counts[a*BL + b*L + l]: a=0 -> src_ids' counts, a=1 -> dst_ids'.
// Each u32 = (count in src row) | (count in dst row) << 16. Padding id 0 -> 0.
__global__ __launch_bounds__(256) void hist_kernel(
    const int* __restrict__ src_ids,
    const int* __restrict__ dst_ids,
    unsigned* __restrict__ counts) {
    __shared__ unsigned hs[HWORDS];
    __shared__ unsigned hd[HWORDS];

    const int b = blockIdx.x;
    const int tid = threadIdx.x;

    for (int i = tid; i < HWORDS; i += 256) { hs[i] = 0u; hd[i] = 0u; }
    __syncthreads();

    const int* __restrict__ srow = src_ids + b * Ln;
    const int* __restrict__ drow = dst_ids + b * Ln;

    // Ln == 512 == 2*blockDim: each thread owns positions tid and tid+256.
    const int s0 = srow[tid], s1 = srow[tid + 256];
    const int d0 = drow[tid], d1 = drow[tid + 256];
    {
        int w;
        w = s0 / 3; atomicAdd(&hs[w], 1u << (10 * (s0 - w * 3)));
        w = s1 / 3; atomicAdd(&hs[w], 1u << (10 * (s1 - w * 3)));
        w = d0 / 3; atomicAdd(&hd[w], 1u << (10 * (d0 - w * 3)));
        w = d1 / 3; atomicAdd(&hd[w], 1u << (10 * (d1 - w * 3)));
    }
    __syncthreads();

    const size_t base = (size_t)b * Ln;
#pragma unroll
    for (int k = 0; k < 2; ++k) {
        const int l = tid + k * 256;
        const int s = (k == 0) ? s0 : s1;
        const int d = (k == 0) ? d0 : d1;
        unsigned ws = 0u, wd = 0u;
        if (s != 0) ws = hist_get(hs, s) | (hist_get(hd, s) << 16);
        if (d != 0) wd = hist_get(hs, d) | (hist_get(hd, d) << 16);
        counts[base + l] = ws;
        counts[BL + base + l] = wd;
    }
}

// Phase 2: pure store-bound expansion, zero LDS, full occupancy.
// One thread per output float4: g = (idx*16 + r), idx = a*BL + p.
__global__ __launch_bounds__(256) void expand_kernel(
    const unsigned* __restrict__ counts,
    const float* __restrict__ table,
    float* __restrict__ out) {
    const unsigned g = blockIdx.x * 256u + threadIdx.x;
    const unsigned r = g & 15u;
    const unsigned idx = g >> 4;  // channel*BL + position
    const unsigned w = counts[idx];           // broadcast within 16-thread group
    const unsigned c0 = w & 0xFFFFu;
    const unsigned c1 = w >> 16;
    const float4 t0 = *((const float4*)(table + c0 * Fn) + r);  // L1-hot rows
    const float4 t1 = *((const float4*)(table + c1 * Fn) + r);
    float4 o;
    o.x = t0.x + t1.x; o.y = t0.y + t1.y; o.z = t0.z + t1.z; o.w = t0.w + t1.w;
    *((float4*)(out + (size_t)idx * Fn) + r) = o;
}

extern "C" void kernel_launch(void* const* d_in, const int* in_sizes, int n_in,
                              void* d_out, int out_size, void* d_ws, size_t ws_size,
                              hipStream_t stream) {
    const int*   src_ids = (const int*)d_in[0];
    const int*   dst_ids = (const int*)d_in[1];
    const float* W1      = (const float*)d_in[2];
    const float* b1      = (const float*)d_in[3];
    const float* W2      = (const float*)d_in[4];
    const float* b2      = (const float*)d_in[5];
    // d_in[6] = num_nodes scalar (20000) — hardcoded as Vn.

    float*    table  = (float*)d_ws;                       // 513*64*4 = 131 KB
    unsigned* counts = (unsigned*)(table + 513 * Fn);      // 2*BL*4 = 2 MB

    build_table_kernel<<<Ln + 1, Fn, 0, stream>>>(W1, b1, W2, b2, table);
    hist_kernel<<<Bn, 256, 0, stream>>>(src_ids, dst_ids, counts);
    // 2*BL positions * 16 float4-slots = 8,388,608 threads = 32768 blocks.
    expand_kernel<<<(2 * BL * 16) / 256, 256, 0, stream>>>(counts, table, (float*)d_out);
}